// Round 14
// baseline (243.600 us; speedup 1.0000x reference)
//
#include <hip/hip_runtime.h>
#include <float.h>

#define N_TRAIN 50000
#define NPAD    50176        // padded col count
#define NBLKS   392          // 128-col shortlist blocks
#define MPAD    1664         // 26*64 padded row count (52 mt32)
#define DDIM    384
#define M_ROWS  1568         // 8*196
#define KNN     20
#define K2      24           // candidate-inclusion rank (margin over 20)
#define SELMAX  64
#define NCLS    21
#define CAPBUF  768
#define NENT    1568         // 392*4 shortlist entries per row

typedef __attribute__((ext_vector_type(8)))  short bf16x8;
typedef __attribute__((ext_vector_type(16))) float f32x16;

#define GLOAD_LDS16(gp, lp) \
  __builtin_amdgcn_global_load_lds((const __attribute__((address_space(1))) void*)(gp), \
                                   (__attribute__((address_space(3))) void*)(lp), 16, 0, 0)

// round-to-nearest-even f32 -> bf16
static __device__ __forceinline__ unsigned short f2bf(float f) {
  unsigned int u = __float_as_uint(f);
  unsigned int r = (u + 0x7fffu + ((u >> 16) & 1u)) >> 16;
  return (unsigned short)r;
}
static __device__ __forceinline__ float bf2f(unsigned short h) {
  return __uint_as_float(((unsigned int)h) << 16);
}
// order-preserving f32 -> u32 key
static __device__ __forceinline__ unsigned int flip32(unsigned int u) {
  return (u & 0x80000000u) ? ~u : (u | 0x80000000u);
}

#define CSW(x, y) { unsigned int _hi = max(x, y); unsigned int _lo = min(x, y); x = _hi; y = _lo; }

// ---------------- transpose labels [256][50000] i32 -> [50000][256] u8 --------
__global__ __launch_bounds__(256) void transpose_labels(const int* __restrict__ labels,
                                                        unsigned char* __restrict__ labT) {
  __shared__ int tile[64][65];
  const int t  = threadIdx.x;
  const int c0 = blockIdx.x * 64;
  const int r0 = blockIdx.y * 64;
#pragma unroll
  for (int i = 0; i < 16; ++i) {
    int idx = i * 256 + t;
    int r = idx >> 6, c = idx & 63;
    int cc = c0 + c;
    tile[r][c] = (cc < N_TRAIN) ? labels[(size_t)(r0 + r) * N_TRAIN + cc] : 0;
  }
  __syncthreads();
#pragma unroll
  for (int i = 0; i < 16; ++i) {
    int idx = i * 256 + t;
    int c = idx >> 6, r = idx & 63;
    int cc = c0 + c;
    if (cc < N_TRAIN) labT[(size_t)cc * 256 + r0 + r] = (unsigned char)tile[r][c];
  }
}

// ------- pack test -> Apack 32x32-frag-major: [mt=52][ks=24][lane=64][8] bf16 --
// element: A[row = mt*32 + (lane&31)][k = ks*16 + (lane>>5)*8 + j]
__global__ __launch_bounds__(256) void conv_Apack(const float* __restrict__ test,
                                                  unsigned short* __restrict__ Apack) {
  int o = blockIdx.x * 256 + threadIdx.x;        // over 52*24*512 = 638,976
  if (o >= (MPAD / 32) * 24 * 512) return;
  int j = o & 7;
  int l = (o >> 3) & 63;
  int rest = o >> 9;
  int ks = rest % 24, mt = rest / 24;
  int row = mt * 32 + (l & 31);
  int k = ks * 16 + (l >> 5) * 8 + j;
  Apack[o] = (row < M_ROWS) ? f2bf(test[(size_t)row * DDIM + k]) : (unsigned short)0;
}

// -- fused: train [384][50000] f32 -> Bpack 32x32-frag-major bf16 + trainT f32 --
// Bpack: [nt=1568][ks=24][lane=64][8]; element B[col=nt*32+(l&31)][k=ks*16+(l>>5)*8+j]
__global__ __launch_bounds__(256) void trans_train_fused(const float* __restrict__ train,
                                                         unsigned short* __restrict__ Bpack,
                                                         float* __restrict__ trainT) {
  __shared__ float tile[64][65];   // [k-in-tile][col-in-tile]
  const int t  = threadIdx.x;
  const int c0 = blockIdx.x * 64;   // col base (0..50176)
  const int r0 = blockIdx.y * 64;   // k base (0..384)
#pragma unroll
  for (int i = 0; i < 16; ++i) {
    int idx = i * 256 + t;
    int r = idx >> 6, c = idx & 63;
    int cc = c0 + c;
    tile[r][c] = (cc < N_TRAIN) ? train[(size_t)(r0 + r) * N_TRAIN + cc] : 0.f;
  }
  __syncthreads();
  // Bpack writes: 512 units of (col, k-oct); each = 16 B contiguous
#pragma unroll
  for (int it = 0; it < 2; ++it) {
    int u = it * 256 + t;
    int c = u & 63, koctL = u >> 6;            // koctL 0..7
    int col = c0 + c;
    int koct = (r0 >> 3) + koctL;              // global k-oct 0..47
    int ks = koct >> 1, half = koct & 1;
    int nt = col >> 5, l = (c & 31) + half * 32;
    size_t base = ((size_t)(nt * 24 + ks) * 64 + l) * 8;
    ushort4 h0, h1;
    h0.x = f2bf(tile[koctL * 8 + 0][c]); h0.y = f2bf(tile[koctL * 8 + 1][c]);
    h0.z = f2bf(tile[koctL * 8 + 2][c]); h0.w = f2bf(tile[koctL * 8 + 3][c]);
    h1.x = f2bf(tile[koctL * 8 + 4][c]); h1.y = f2bf(tile[koctL * 8 + 5][c]);
    h1.z = f2bf(tile[koctL * 8 + 6][c]); h1.w = f2bf(tile[koctL * 8 + 7][c]);
    *(ushort4*)&Bpack[base]     = h0;
    *(ushort4*)&Bpack[base + 4] = h1;
  }
#pragma unroll
  for (int i = 0; i < 16; ++i) {
    int idx = i * 256 + t;
    int c = idx >> 6, r = idx & 63;
    int cc = c0 + c;
    if (cc < N_TRAIN) trainT[(size_t)cc * DDIM + r0 + r] = tile[r][c];
  }
}

// ---------------- MFMA 32x32x16 GEMM: A-in-LDS, B reg-streamed, hi-occupancy --
// Block: 512 thr, 8 waves (2m x 4n), wave = 32 rows x 128 cols (4 frags of
// 32x32). Block covers 64 rows x (2 steps x 512 cols). A tile 64x384 = 48KB
// LDS, staged once; ZERO main-loop barriers. launch_bounds(512,4) -> VGPR<=128
// -> 4 waves/SIMD (2 blocks/CU).
__global__ __launch_bounds__(512, 4) void mfma_gemm(const unsigned short* __restrict__ Apack,
                                                    const unsigned short* __restrict__ Bpack,
                                                    unsigned int* __restrict__ toplist) {
  __shared__ unsigned short Al[24576];   // 48 KB
  __shared__ uint4 bounce[64 * 4];       //  4 KB
  const int t = threadIdx.x;

  // bijective XCD chunking: nwg = 1274 = 8*159 + 2
  const int flat = blockIdx.x;
  const int xcd = flat & 7, jj = flat >> 3;
  const int wg = (xcd < 2 ? xcd * 160 : 320 + (xcd - 2) * 159) + jj;
  const int mblk = wg % 26, ngrp = wg / 26;   // 26 consecutive wg share ngrp
  const int m0 = mblk * 64;

  const int wid = t >> 6, lane = t & 63;
  const int wr = wid >> 2, wc = wid & 3;      // 2 x 4 waves; wave 32 rows x 128 cols
  const int l31 = lane & 31, lh = lane >> 5;

  // ---- stage A once: 48KB linear copy of Apack block region ----
  const unsigned short* Asrc = Apack + (size_t)(mblk * 2) * 24 * 512;
#pragma unroll
  for (int j = 0; j < 6; ++j)
    GLOAD_LDS16(Asrc + (size_t)j * 4096 + wid * 512 + lane * 8,
                &Al[j * 4096 + wid * 512]);
  __syncthreads();   // drains vmcnt before barrier

#pragma unroll 1
  for (int s = 0; s < 2; ++s) {
    const int colbase = ngrp * 1024 + s * 512;
    const unsigned short* Bb = Bpack + (size_t)((colbase >> 5) + wc * 4) * 24 * 512;

    f32x16 acc[4];
#pragma unroll
    for (int n = 0; n < 4; ++n)
#pragma unroll
      for (int q = 0; q < 16; ++q) acc[n][q] = 0.f;

#pragma unroll 4
    for (int ks = 0; ks < 24; ++ks) {
      bf16x8 a = *(const bf16x8*)&Al[((wr * 24 + ks) * 64 + lane) * 8];
      bf16x8 b[4];
#pragma unroll
      for (int n = 0; n < 4; ++n)
        b[n] = *(const bf16x8*)&Bb[((size_t)(n * 24 + ks) * 64 + lane) * 8];
#pragma unroll
      for (int n = 0; n < 4; ++n)
        acc[n] = __builtin_amdgcn_mfma_f32_32x32x16_bf16(a, b[n], acc[n], 0, 0, 0);
    }

    // ---- epilogue: per-row top-4 over this wave's 128 cols ----
    // C layout: col = n*32 + l31 (+wave/col bases); row = (reg&3)+8*(reg>>2)+4*lh
#pragma unroll
    for (int reg = 0; reg < 16; ++reg) {
      const int rowl = (reg & 3) + 8 * (reg >> 2) + 4 * lh;   // 0..31
      unsigned int v0, v1, v2, v3;
      {
        unsigned int e[4];
#pragma unroll
        for (int n = 0; n < 4; ++n) {
          int col = colbase + wc * 128 + n * 32 + l31;
          unsigned int k16 = flip32(__float_as_uint(acc[n][reg])) >> 16;
          e[n] = (col < N_TRAIN) ? ((k16 << 16) | (0xFFFFu - (unsigned int)col)) : 0u;
        }
        CSW(e[0], e[1]); CSW(e[2], e[3]); CSW(e[0], e[2]); CSW(e[1], e[3]); CSW(e[1], e[2]);
        v0 = e[0]; v1 = e[1]; v2 = e[2]; v3 = e[3];
      }
      // butterfly merge across 32 l31-lanes (strides 1..16, stays in lane-half)
#pragma unroll
      for (int st = 1; st <= 16; st <<= 1) {
        unsigned int p0 = (unsigned int)__shfl_xor((int)v0, st);
        unsigned int p1 = (unsigned int)__shfl_xor((int)v1, st);
        unsigned int p2 = (unsigned int)__shfl_xor((int)v2, st);
        unsigned int p3 = (unsigned int)__shfl_xor((int)v3, st);
        unsigned int t0 = max(v0, p3), t1 = max(v1, p2);
        unsigned int t2 = max(v2, p1), t3 = max(v3, p0);
        CSW(t0, t2); CSW(t1, t3); CSW(t0, t1); CSW(t2, t3);
        v0 = t0; v1 = t1; v2 = t2; v3 = t3;
      }
      if (l31 == 0) {
        uint4 w; w.x = v0; w.y = v1; w.z = v2; w.w = v3;
        bounce[(wr * 32 + rowl) * 4 + wc] = w;
      }
    }
    __syncthreads();

    // ---- coalesced shortlist writeout: [row][blk*4..+3] ----
    if (t < 256) {
      int row = t >> 2, e = t & 3;
      int grow = m0 + row;
      if (grow < M_ROWS) {
        uint4 w = bounce[row * 4 + e];
        int blk = (colbase >> 7) + e;
        *(uint4*)&toplist[(size_t)grow * NENT + blk * 4] = w;
      }
    }
    __syncthreads();   // bounce reused next step
  }
}

// --------- fused tail: shortlist select (+rare rescan) -> f64 refine -> vote --
__global__ __launch_bounds__(256) void tail_fused(const unsigned int* __restrict__ toplist,
                                                  const float* __restrict__ test,
                                                  const float* __restrict__ trainT,
                                                  const unsigned char* __restrict__ labT,
                                                  int* __restrict__ out) {
  const int t = threadIdx.x, m = blockIdx.x;
  __shared__ unsigned int ent[NENT];
  __shared__ unsigned int smax[256];
  __shared__ unsigned int sbuf[CAPBUF];
  __shared__ unsigned int scnt, sTauA, sE24, ccnt2;
  __shared__ unsigned char flg[NBLKS];
  __shared__ short flist[64];
  __shared__ int fcnt, sC2;
  __shared__ unsigned int cbuf[128];
  __shared__ int    selC[SELMAX];
  __shared__ double rvs[SELMAX];
  __shared__ double sv2[SELMAX];
  __shared__ int    si2[SELMAX];
  __shared__ double earr[KNN];
  __shared__ double wv[KNN];
  __shared__ int    wi[KNN];

  if (t == 0) { scnt = 0u; fcnt = 0; ccnt2 = 0u; sC2 = 0; }
  for (int i = t; i < NENT; i += 256) ent[i] = toplist[(size_t)m * NENT + i];
  __syncthreads();

  // tauA = 24th largest of per-thread maxima (ties by tid)
  unsigned int mx = 0u;
  for (int i = t; i < NENT; i += 256) mx = max(mx, ent[i]);
  smax[t] = mx;
  __syncthreads();
  {
    int rnk = 0;
    for (int j = 0; j < 256; ++j)
      rnk += (smax[j] > mx || (smax[j] == mx && j < t)) ? 1 : 0;
    if (rnk == K2 - 1) sTauA = mx;
  }
  __syncthreads();
  const unsigned int tauA = sTauA;

  // collect entries >= tauA; find e24 = 24th-largest entry (u32 unique)
  for (int i = t; i < NENT; i += 256) {
    unsigned int e = ent[i];
    if (e >= tauA) { unsigned int p = atomicAdd(&scnt, 1u); if (p < CAPBUF) sbuf[p] = e; }
  }
  __syncthreads();
  const int C = (int)min(scnt, (unsigned int)CAPBUF);
  for (int s = t; s < C; s += 256) {
    unsigned int e = sbuf[s];
    int rk = 0;
    for (int j = 0; j < C; ++j) rk += (sbuf[j] > e) ? 1 : 0;
    if (rk == K2 - 1) sE24 = e;
  }
  __syncthreads();
  const unsigned int k24 = sE24 >> 16;

  // flag blocks whose 4th shortlist key >= k24 (may hide >4 elems above k24)
  for (int i = t; i < NBLKS; i += 256) {
    bool fl = (ent[i * 4 + 3] >> 16) >= k24;
    flg[i] = fl ? 1 : 0;
    if (fl) { int p = atomicAdd(&fcnt, 1); if (p < 64) flist[p] = (short)i; }
  }
  __syncthreads();

  // candidates: non-flagged shortlist entries with key >= k24
  for (int i = t; i < NENT; i += 256) {
    unsigned int e = ent[i];
    if ((e >> 16) >= k24) {
      int col = 0xFFFF - (int)(e & 0xFFFFu);
      if (!flg[col >> 7]) { unsigned int p = atomicAdd(&ccnt2, 1u); if (p < 128) cbuf[p] = e; }
    }
  }
  __syncthreads();

  // rescan flagged blocks fully (bf16-rounded f32 dot; 1-ulp slack on key)
  const int FC = min(fcnt, 64);
  for (int q = 0; q < FC; ++q) {
    const int fb = flist[q];
    const int col = fb * 128 + t;
    if (t < 128 && col < N_TRAIN) {
      const float* Tc = trainT + (size_t)col * DDIM;
      const float* Tr = test + (size_t)m * DDIM;
      float s0 = 0.f;
      for (int k = 0; k < DDIM; ++k)
        s0 = fmaf(bf2f(f2bf(Tr[k])), bf2f(f2bf(Tc[k])), s0);
      unsigned int key = flip32(__float_as_uint(s0)) >> 16;
      if (key + 1u >= k24) {
        unsigned int e = (key << 16) | (0xFFFFu - (unsigned int)col);
        unsigned int p = atomicAdd(&ccnt2, 1u);
        if (p < 128) cbuf[p] = e;
      }
    }
  }
  __syncthreads();
  const int CC = (int)min(ccnt2, 128u);

  // rank-select candidates by (key desc, col asc) == u32 desc -> selC[0..C2)
  for (int s = t; s < CC; s += 256) {
    unsigned int e = cbuf[s];
    int rk = 0;
    for (int j = 0; j < CC; ++j) rk += (cbuf[j] > e) ? 1 : 0;
    if (rk < SELMAX) {
      selC[rk] = 0xFFFF - (int)(e & 0xFFFFu);
      atomicMax(&sC2, rk + 1);
    }
  }
  __syncthreads();
  const int C2 = sC2 < SELMAX ? sC2 : SELMAX;   // >= 20 guaranteed

  // ---- f64 refine of C2 cands (4 waves split cands, lanes over d) ----
  const int wid = t >> 6, lane = t & 63;
  float tr[DDIM / 64];
#pragma unroll
  for (int dd = 0; dd < DDIM / 64; ++dd)
    tr[dd] = test[(size_t)m * DDIM + dd * 64 + lane];
#pragma unroll 1
  for (int c = wid; c < C2; c += 4) {
    const float* Tc = trainT + (size_t)selC[c] * DDIM;
    double s = 0.0;
#pragma unroll
    for (int dd = 0; dd < DDIM / 64; ++dd)
      s += (double)tr[dd] * (double)Tc[dd * 64 + lane];
#pragma unroll
    for (int off = 32; off > 0; off >>= 1) s += __shfl_xor(s, off);
    if (lane == 0) rvs[c] = s;
  }
  __syncthreads();

  if (t < C2) {
    double v = rvs[t]; int id = selC[t];
    int r = 0;
    for (int n = 0; n < C2; ++n)
      r += (rvs[n] > v || (rvs[n] == v && selC[n] < id)) ? 1 : 0;
    sv2[r] = v; si2[r] = id;
  }
  __syncthreads();

  if (t < KNN) earr[t] = exp(sv2[t] - sv2[0]);
  __syncthreads();
  if (t < KNN) {
    double ssum = 0.0;
    for (int k = 0; k < KNN; ++k) ssum += earr[k];
    wv[t] = earr[t] / ssum;
    wi[t] = si2[t];
  }
  __syncthreads();

  // ---- per-pixel weighted vote (f64) + argmax ----
  unsigned int packed[5];
#pragma unroll
  for (int q = 0; q < 5; ++q) {
    unsigned int p = 0;
#pragma unroll
    for (int j = 0; j < 4; ++j)
      p |= (unsigned int)labT[(size_t)wi[q * 4 + j] * 256 + t] << (8 * j);
    packed[q] = p;
  }
  double best = -1.0; int bc = 0;
#pragma unroll 1
  for (int c = 0; c < NCLS; ++c) {
    double s = 0.0;
#pragma unroll
    for (int k = 0; k < KNN; ++k) {
      unsigned int lab = (packed[k >> 2] >> ((k & 3) * 8)) & 255u;
      s += (lab == (unsigned int)c) ? wv[k] : 0.0;
    }
    if (s > best) { best = s; bc = c; }
  }
  const int b = m / 196, p = m % 196;
  const int py = p / 14, px = p % 14;
  const int i = t >> 4, j = t & 15;
  out[((size_t)b * 224 + py * 16 + i) * 224 + px * 16 + j] = bc;
}

// ---------------- launch ------------------------------------------------------
// ws layout (bytes), total 139,247,616 (< ~307 MB poisoned ws):
//   labT    @ 0           : 12,800,000
//   Apack   @ 12,800,000  :  1,277,952  (u16 [52][24][64][8])
//   Bpack   @ 14,077,952  : 38,535,168  (u16 [1568][24][64][8])
//   trainT  @ 52,613,120  : 76,800,000  (f32 [50000][384])
//   toplist @ 129,413,120 :  9,834,496  (u32 [1568][1568])
extern "C" void kernel_launch(void* const* d_in, const int* in_sizes, int n_in,
                              void* d_out, int out_size, void* d_ws, size_t ws_size,
                              hipStream_t stream) {
  const float* test  = (const float*)d_in[0];   // [1568][384]
  const float* train = (const float*)d_in[1];   // [384][50000]
  const int* labels  = (const int*)d_in[2];     // [256][50000]
  int* out = (int*)d_out;
  char* ws = (char*)d_ws;

  unsigned char*  labT    = (unsigned char*)ws;
  unsigned short* Apack   = (unsigned short*)(ws + 12800000);
  unsigned short* Bpack   = (unsigned short*)(ws + 14077952);
  float*          trainT  = (float*)(ws + 52613120);
  unsigned int*   toplist = (unsigned int*)(ws + 129413120);

  transpose_labels<<<dim3(782, 4), 256, 0, stream>>>(labels, labT);
  conv_Apack<<<dim3((MPAD / 32) * 24 * 512 / 256), 256, 0, stream>>>(test, Apack);
  trans_train_fused<<<dim3(784, 6), 256, 0, stream>>>(train, Bpack, trainT);
  mfma_gemm<<<dim3(1274), 512, 0, stream>>>(Apack, Bpack, toplist);
  tail_fused<<<dim3(M_ROWS), 256, 0, stream>>>(toplist, test, trainT, labT, out);
}